// Round 8
// baseline (353.785 us; speedup 1.0000x reference)
//
#include <hip/hip_runtime.h>
#include <math.h>

// Problem constants (fixed by setup_inputs)
#define BATCH 8192
#define EDIM  4096
#define NBINS 64        // 8x8 pair-histogram bins
#define NGRP  128       // field row-groups (2048 waves total)
#define ROWSW (BATCH / NGRP)   // 64 rows per wave
#define NCHK  16        // column chunks of 256

// Workspace layout (floats/u32). Measured ws_size = 512 MiB (R6 poison fill),
// we use ~9.06 MB.
#define OFF_HISTP   0u                           // 8192*64 u32 per-block hist
#define OFF_CSP     (2u * 1024 * 1024 / 4)       // 128*4096 f32 colsum partials
#define OFF_CQP     (4u * 1024 * 1024 / 4)
#define OFF_PPP     (6u * 1024 * 1024 / 4)
#define OFF_RFSQP   (8u * 1024 * 1024 / 4)       // 16*8192 f32 row-sumsq partials
#define OFF_ROWENT  (OFF_RFSQP + NCHK * BATCH)
#define OFF_ROWSTD  (OFF_ROWENT + BATCH)
#define OFF_ROWFSQ  (OFF_ROWSTD + BATCH)
#define OFF_COLSUM  (OFF_ROWFSQ + BATCH)
#define OFF_COLSQ   (OFF_COLSUM + EDIM)
#define OFF_PAIRP   (OFF_COLSQ + EDIM)
#define OFF_HIST2   (OFF_PAIRP + EDIM)           // 8*64 u32

// Fused streaming pass: 8704 blocks = 8192 psi-row blocks + 512 field-tile
// blocks, interleaved 16:1 so both input streams overlap on the machine
// (two serial ~75 us passes -> one pass against the 42 us combined-traffic
// floor). Whole block takes one path -> no divergence.
__global__ __launch_bounds__(256) void main_pass(const float* __restrict__ psi,
                                                 const float* __restrict__ f,
                                                 unsigned* __restrict__ hist_part,
                                                 float* __restrict__ row_ent,
                                                 float* __restrict__ row_std,
                                                 float* __restrict__ cs_part,
                                                 float* __restrict__ cq_part,
                                                 float* __restrict__ pp_part,
                                                 float* __restrict__ rfsq_part) {
  const int b = blockIdx.x;
  const int grp = b / 17;          // 0..511
  const int sub = b - grp * 17;    // 0..16
  const int t = threadIdx.x;

  __shared__ unsigned lhist[NBINS];
  __shared__ float firsts[EDIM / 4];
  __shared__ float red[12];

  if (sub == 16) {
    // ---------------- field tile: 4 waves, each 256 cols x 64 rows ---------
    const int gw = grp * 4 + (t >> 6);     // 0..2047
    const int lane = t & 63;
    const int cchunk = gw & (NCHK - 1);
    const int g = gw >> 4;                 // row group 0..127
    const int c0 = cchunk * 256 + lane * 4;
    const int r0 = g * ROWSW;

    float cs0 = 0.f, cs1 = 0.f, cs2 = 0.f, cs3 = 0.f;
    float cq0 = 0.f, cq1 = 0.f, cq2 = 0.f, cq3 = 0.f;
    float pp0 = 0.f, pp1 = 0.f, pp2 = 0.f, pp3 = 0.f;
#pragma unroll 8
    for (int i = 0; i < ROWSW; ++i) {
      const int r = r0 + i;
      const float4 v = *(const float4*)(f + (size_t)r * EDIM + c0);
      cs0 += v.x; cs1 += v.y; cs2 += v.z; cs3 += v.w;
      cq0 = fmaf(v.x, v.x, cq0); cq1 = fmaf(v.y, v.y, cq1);
      cq2 = fmaf(v.z, v.z, cq2); cq3 = fmaf(v.w, v.w, cq3);
      pp0 = fmaf(v.x, v.y, pp0); pp1 = fmaf(v.y, v.z, pp1); pp2 = fmaf(v.z, v.w, pp2);
      float nx = __shfl_down(v.x, 1);            // next lane's first column
      if (lane != 63) pp3 = fmaf(v.w, nx, pp3);  // boundary pairs in reduce_pass
      float rs = fmaf(v.x, v.x, fmaf(v.y, v.y, fmaf(v.z, v.z, v.w * v.w)));
      for (int off = 32; off; off >>= 1) rs += __shfl_down(rs, off);
      if (lane == 0) rfsq_part[(size_t)cchunk * BATCH + r] = rs;  // plain store
    }
    const size_t cb = (size_t)g * EDIM + c0;
    *(float4*)(cs_part + cb) = make_float4(cs0, cs1, cs2, cs3);
    *(float4*)(cq_part + cb) = make_float4(cq0, cq1, cq2, cq3);
    *(float4*)(pp_part + cb) = make_float4(pp0, pp1, pp2, pp3);  // lane63 slot = 0
    return;
  }

  // ---------------- psi row: entropy, std, 64-bin pair histogram ----------
  const int r = grp * 16 + sub;          // 0..8191
  const float4* row = (const float4*)(psi + (size_t)r * EDIM);

  if (t < NBINS) lhist[t] = 0u;

  float4 v[4];
#pragma unroll
  for (int k = 0; k < 4; ++k) v[k] = row[t + k * 256];
#pragma unroll
  for (int k = 0; k < 4; ++k) firsts[t + k * 256] = v[k].x;
  __syncthreads();   // covers lhist zero-init + firsts visibility

  float s = 0.f, sq = 0.f, pl = 0.f;
#pragma unroll
  for (int k = 0; k < 4; ++k) {
    const int vi = t + k * 256;
    float ee[4] = {v[k].x, v[k].y, v[k].z, v[k].w};
    int q[4];
#pragma unroll
    for (int j = 0; j < 4; ++j) {
      float x = ee[j];
      s += x;
      sq = fmaf(x, x, sq);
      pl = fmaf(x, __logf(x + 1e-10f), pl);  // accuracy non-critical: d_eeg clamps
      int qq = (int)floorf(x * 8.0f);
      q[j] = min(max(qq, 0), 7);
    }
#pragma unroll
    for (int j = 0; j < 3; ++j)
      atomicAdd(&lhist[q[j] * 8 + q[j + 1]], 1u);   // LDS-scope atomic: cheap
    if (vi < EDIM / 4 - 1) {
      float xn = firsts[vi + 1];
      int qn = min(max((int)floorf(xn * 8.0f), 0), 7);
      atomicAdd(&lhist[q[3] * 8 + qn], 1u);
    }
  }

  for (int off = 32; off; off >>= 1) {
    s  += __shfl_down(s, off);
    sq += __shfl_down(sq, off);
    pl += __shfl_down(pl, off);
  }
  const int w = t >> 6, lane = t & 63;
  if (lane == 0) { red[w] = s; red[4 + w] = sq; red[8 + w] = pl; }
  __syncthreads();   // also guarantees all lhist atomics have landed
  if (t == 0) {
    float S  = red[0] + red[1] + red[2] + red[3];
    float SQ = red[4] + red[5] + red[6] + red[7];
    float PL = red[8] + red[9] + red[10] + red[11];
    row_ent[r] = -PL;
    float var = (SQ - S * S / (float)EDIM) / (float)(EDIM - 1);
    row_std[r] = sqrtf(fmaxf(var, 0.f));
  }
  if (t < NBINS) hist_part[(size_t)r * NBINS + t] = lhist[t];
}

// Folds partials. Blocks 0..15 colsum, 16..31 colsumsq, 32..47 pairprod
// (non-boundary), 48..79 row_fsq, 80..87 histogram (->8 reps), 88..102
// boundary pair columns (f is L2/L3-hot).
__global__ __launch_bounds__(256) void reduce_pass(const float* __restrict__ f,
                                                   const unsigned* __restrict__ hist_part,
                                                   const float* __restrict__ cs_part,
                                                   const float* __restrict__ cq_part,
                                                   const float* __restrict__ pp_part,
                                                   const float* __restrict__ rfsq_part,
                                                   float* __restrict__ colsum,
                                                   float* __restrict__ colsumsq,
                                                   float* __restrict__ pairprod,
                                                   float* __restrict__ row_fsq,
                                                   unsigned* __restrict__ hist2) {
  const int b = blockIdx.x;
  const int t = threadIdx.x;

  if (b < 48) {                       // column-stat folds
    const int stat = b >> 4;          // 0 cs, 1 cq, 2 pp
    const int c = (b & 15) * 256 + t;
    const float* part = (stat == 0) ? cs_part : (stat == 1) ? cq_part : pp_part;
    float acc = 0.f;
#pragma unroll 8
    for (int g = 0; g < NGRP; ++g) acc += part[(size_t)g * EDIM + c];
    if (stat == 0) colsum[c] = acc;
    else if (stat == 1) colsumsq[c] = acc;
    else if ((c & 255) != 255) pairprod[c] = acc;  // boundary cols from blocks 88+
  } else if (b < 80) {                // row_fsq fold
    const int r = (b - 48) * 256 + t;
    float acc = 0.f;
#pragma unroll
    for (int k = 0; k < NCHK; ++k) acc += rfsq_part[(size_t)k * BATCH + r];
    row_fsq[r] = acc;
  } else if (b < 88) {                // histogram: 1024 psi-rows -> 1 replica
    __shared__ unsigned hred[4][NBINS];
    const int j = b - 80;
    const int bin = t & 63, quad = t >> 6;
    unsigned acc = 0u;
    for (int pb = j * 1024 + quad; pb < (j + 1) * 1024; pb += 4)
      acc += hist_part[(size_t)pb * NBINS + bin];
    hred[quad][bin] = acc;
    __syncthreads();
    if (t < NBINS)
      hist2[(size_t)j * NBINS + t] = hred[0][t] + hred[1][t] + hred[2][t] + hred[3][t];
  } else {                            // boundary pair columns c=255,511,...,3839
    __shared__ float sred[4];
    const int c = (b - 88) * 256 + 255;
    float acc = 0.f;
    for (int r = t; r < BATCH; r += 256)
      acc = fmaf(f[(size_t)r * EDIM + c], f[(size_t)r * EDIM + c + 1], acc);
    for (int off = 32; off; off >>= 1) acc += __shfl_down(acc, off);
    if ((t & 63) == 0) sred[t >> 6] = acc;
    __syncthreads();
    if (t == 0) pairprod[c] = sred[0] + sred[1] + sred[2] + sred[3];
  }
}

__device__ double blk_reduce(double v, double* sbuf) {
  const int t = threadIdx.x;
  for (int off = 32; off; off >>= 1) v += __shfl_down(v, off);
  __syncthreads();                 // protect sbuf against reuse from prior call
  if ((t & 63) == 0) sbuf[t >> 6] = v;
  __syncthreads();
  return sbuf[0] + sbuf[1] + sbuf[2] + sbuf[3];
}

__global__ __launch_bounds__(256) void finalize(const unsigned* __restrict__ hist2,
                                                const float* __restrict__ row_ent,
                                                const float* __restrict__ row_std,
                                                const float* __restrict__ row_fsq,
                                                const float* __restrict__ colsum,
                                                const float* __restrict__ colsumsq,
                                                const float* __restrict__ pairprod,
                                                const float* __restrict__ wts,
                                                float* __restrict__ out) {
  const int t = threadIdx.x;
  __shared__ double sbuf[4];

  double se = 0, ss = 0, sm = 0;
  for (int i = t; i < BATCH; i += 256) {
    se += (double)row_ent[i];
    ss += (double)row_std[i];
    sm += (double)sqrtf(row_fsq[i]);
  }
  double SE = blk_reduce(se, sbuf);
  double SS = blk_reduce(ss, sbuf);
  double SM = blk_reduce(sm, sbuf);

  // adjacent-column Pearson corr from uncentered sums (double for the
  // cancellation-heavy cov term; this is the only unclamped, sensitive stat)
  double csum = 0, ccnt = 0;
  for (int e = t; e < EDIM - 1; e += 256) {
    double sa = colsum[e], sb = colsum[e + 1];
    double va = (double)colsumsq[e]     - sa * sa / (double)BATCH;
    double vb = (double)colsumsq[e + 1] - sb * sb / (double)BATCH;
    double cov = (double)pairprod[e] - sa * sb / (double)BATCH;
    double corr = cov / sqrt(va * vb);
    if (!isnan(corr)) { csum += corr; ccnt += 1.0; }
  }
  double CS = blk_reduce(csum, sbuf);
  double CN = blk_reduce(ccnt, sbuf);

  double gs = 0, gq = 0;
  for (int e = t; e < EDIM; e += 256) { gs += (double)colsum[e]; gq += (double)colsumsq[e]; }
  double GS = blk_reduce(gs, sbuf);
  double GQ = blk_reduce(gq, sbuf);

  double hent = 0;
  if (t < NBINS) {
    unsigned long long cnt = 0;
#pragma unroll
    for (int j = 0; j < 8; ++j) cnt += (unsigned long long)hist2[j * NBINS + t];
    const double total = (double)BATCH * (double)(EDIM - 1);
    double p = (double)cnt / total;
    if (p > 0.0) hent = -p * log2(p);
  }
  double HE = blk_reduce(hent, sbuf);

  if (t == 0) {
    double entropy = SE / (double)BATCH;
    double spat = SS / (double)BATCH;
    double d_eeg = fmin(entropy * spat * 3.0, 10.0);

    double mag = SM / (double)BATCH;
    double mean_corr = (CN > 0.0) ? (CS / CN) : 0.0;
    double h_fmri = fmin(mag * fabs(mean_corr) * 2.0, 5.0);

    double Nf = (double)BATCH * (double)EDIM;
    double gvar = (GQ - GS * GS / Nf) / (Nf - 1.0);
    double fstd = sqrt(fmax(gvar, 0.0));
    double clz = fmin(HE + 0.3 * fstd, 3.0);

    double fci = (double)wts[0] * (d_eeg / 10.0)
               + (double)wts[1] * (h_fmri / 5.0)
               + (double)wts[2] * (clz / 3.0);
    fci = fmin(fmax(fci, 0.0), 1.0);
    out[0] = (float)fci;
  }
}

extern "C" void kernel_launch(void* const* d_in, const int* in_sizes, int n_in,
                              void* d_out, int out_size, void* d_ws, size_t ws_size,
                              hipStream_t stream) {
  const float* psi = (const float*)d_in[0];
  const float* fld = (const float*)d_in[1];
  const float* wts = (const float*)d_in[2];
  float* out = (float*)d_out;
  float* ws = (float*)d_ws;

  unsigned* hist_part = (unsigned*)(ws + OFF_HISTP);
  float* cs_part   = ws + OFF_CSP;
  float* cq_part   = ws + OFF_CQP;
  float* pp_part   = ws + OFF_PPP;
  float* rfsq_part = ws + OFF_RFSQP;
  float* row_ent   = ws + OFF_ROWENT;
  float* row_std   = ws + OFF_ROWSTD;
  float* row_fsq   = ws + OFF_ROWFSQ;
  float* colsum    = ws + OFF_COLSUM;
  float* colsumsq  = ws + OFF_COLSQ;
  float* pairprod  = ws + OFF_PAIRP;
  unsigned* hist2  = (unsigned*)(ws + OFF_HIST2);

  // No memset needed: every consumed workspace cell is fully written upstream.
  main_pass<<<8704, 256, 0, stream>>>(psi, fld, hist_part, row_ent, row_std,
                                      cs_part, cq_part, pp_part, rfsq_part);
  reduce_pass<<<103, 256, 0, stream>>>(fld, hist_part, cs_part, cq_part, pp_part,
                                       rfsq_part, colsum, colsumsq, pairprod, row_fsq, hist2);
  finalize<<<1, 256, 0, stream>>>(hist2, row_ent, row_std, row_fsq,
                                  colsum, colsumsq, pairprod, wts, out);
}